// Round 12
// baseline (296.153 us; speedup 1.0000x reference)
//
#include <hip/hip_runtime.h>
#include <math.h>

// SSM_18597208391915: HiPPO-LegT recurrence, O(N) semiseparable solve.
// Ad = (I-cA)^{-1}(I+cA) = 2M - I  =>  h' = tanh(2*M(h + c*u*P) - h).
// R10 (WIN, 231us): NW=4 chunked skewed wave pipeline, 2 indep waves/SIMD.
// R11 FAILED: v_fmac_f32_dpp inline asm corrupted the scan -- inline asm is
// opaque to the GCN hazard recognizer, so the VALU-write->DPP-read wait
// states were not inserted. R12: revert to R10's builtin update_dpp + fma
// chain (compiler inserts hazard nops); KEEP the rcp-free tanh:
//   tanh(g) = sign * (1-z)/(1+z), z = 2^{-|s|}, s = 2*log2e*g;
//   1/(1+z) via Newton (seed 16/17 - 8/17 z, 2 iters, rel err (1/17)^4)
// -- all full-rate packed fma, removes 64 cyc/step of quarter-rate v_rcp.
// Single scaled state hs = 2*log2(e)*h.

#define SEQ     784
#define OUT_DIM 10
#define NW      4
#define CH      16            // steps per chunk
#define NCH     (SEQ/CH)      // 49
#define EPL     4             // elems/lane: NW*64*EPL = 1024 = HIDDEN
#define NG      (EPL/2)

typedef float v2f __attribute__((ext_vector_type(2)));

#if __has_builtin(__builtin_elementwise_fma)
__device__ __forceinline__ v2f fma2(v2f a, v2f b, v2f c) {
    return __builtin_elementwise_fma(a, b, c);
}
#else
__device__ __forceinline__ v2f fma2(v2f a, v2f b, v2f c) {
    v2f r; r.x = fmaf(a.x, b.x, c.x); r.y = fmaf(a.y, b.y, c.y); return r;
}
#endif

#if __has_builtin(__builtin_elementwise_min)
__device__ __forceinline__ v2f min2(v2f a, v2f b) {
    return __builtin_elementwise_min(a, b);
}
#else
__device__ __forceinline__ v2f min2(v2f a, v2f b) {
    v2f r; r.x = fminf(a.x, b.x); r.y = fminf(a.y, b.y); return r;
}
#endif

#if __has_builtin(__builtin_amdgcn_exp2f)
#define EXP2F(x) __builtin_amdgcn_exp2f(x)
#else
#define EXP2F(x) __expf(0.69314718055994531f * (x))
#endif

// DPP move: result = src shuffled per CTRL; invalid/masked lanes get `old`.
// (builtin form: compiler handles the VALU->DPP hazard wait states)
template<int CTRL, int ROW_MASK>
__device__ __forceinline__ float dpp_mov(float src, float old) {
    return __int_as_float(__builtin_amdgcn_update_dpp(
        __float_as_int(old), __float_as_int(src), CTRL, ROW_MASK, 0xf, false));
}
// DPP ctrls: row_shr:N = 0x110|N, row_bcast15 = 0x142, row_bcast31 = 0x143,
//            wave_shr:1 = 0x138 (whole-wave shift down one lane)

__global__ __launch_bounds__(256, 2)
void ssm_hippo_scan(const float* __restrict__ x,     // (512, 784)
                    const float* __restrict__ C,     // (1024)
                    const float* __restrict__ W,     // (10)
                    const float* __restrict__ bvec,  // (10)
                    float* __restrict__ out)         // (512, 10)
{
    const int b    = blockIdx.x;
    const int tid  = threadIdx.x;
    const int wv   = tid >> 6;       // wave w owns elems [w*256, w*256+256)
    const int lane = tid & 63;

    __shared__ __align__(16) float u_s[SEQ];
    __shared__ __align__(16) float totB_s[NW-1][SEQ]; // inclusive-B streams
    __shared__ double part_s[NW];

    for (int t = tid; t < SEQ; t += 256) u_s[t] = x[b * SEQ + t];

    const double hdt  = 0.5 / (double)SEQ;            // c = dt/2
    const double L2E2 = 2.0 * 1.4426950408889634;     // 2*log2(e)

    // ---- per-element constants (n = wv*256 + lane*EPL + i), fp64-derived
    v2f upc2[NG], nhdtP2[NG], pdin2[NG], invd2v[NG], aprod2[NG];
    v2f aprel2;                 // {1, alphas[2]}: hi-chain fixup
    float alphas[EPL], apH;
    float Alev0, Alev1, Alev2, Alev3, Alev4, Alev5, Aexcl;
    {
        double apd = 1.0;
#pragma unroll
        for (int i = 0; i < EPL; ++i) {
            const int    n = wv * 256 + lane * EPL + i;
            const double p = sqrt(1.0 + 2.0 * (double)n);
            const double d = 1.0 + hdt * (double)(n + 1);
            const double a = 1.0 - hdt * p * p / d;
            upc2[i>>1][i&1]   = (float)(L2E2 * hdt * p);
            nhdtP2[i>>1][i&1] = (float)(-hdt * p);
            pdin2[i>>1][i&1]  = (float)(p / d);
            invd2v[i>>1][i&1] = (float)(2.0 / d);
            alphas[i]         = (float)a;
            aprod2[i>>1][i&1] = (float)apd;
            apd *= a;
        }
        aprel2 = (v2f){1.0f, alphas[2]};
        apH    = alphas[2] * alphas[3];
        float A = (float)apd;
        Alev0 = A; A *= dpp_mov<0x111, 0xf>(A, 1.0f);
        Alev1 = A; A *= dpp_mov<0x112, 0xf>(A, 1.0f);
        Alev2 = A; A *= dpp_mov<0x114, 0xf>(A, 1.0f);
        Alev3 = A; A *= dpp_mov<0x118, 0xf>(A, 1.0f);
        Alev4 = A; A *= dpp_mov<0x142, 0xa>(A, 1.0f);
        Alev5 = A; A *= dpp_mov<0x143, 0xc>(A, 1.0f);
        Aexcl = dpp_mov<0x138, 0xf>(A, 1.0f);   // lane0 -> 1 (excl alpha prod)
    }

    // inter-wave composition: Tin(w)[s] = sum_{v<w} cin_v * B_v[s]
    float cF1 = 0.0f, cF2 = 0.0f, cF12 = 0.0f;
    {
        double n1 = 1.0, d1 = 1.0, n2 = 1.0, d2 = 1.0;
        for (int n = 256; n < 512; ++n) {
            n1 *= 1.0 - hdt * (double)n; d1 *= 1.0 + hdt * (double)(n + 1);
        }
        for (int n = 512; n < 768; ++n) {
            n2 *= 1.0 - hdt * (double)n; d2 *= 1.0 + hdt * (double)(n + 1);
        }
        const double Phi1 = n1 / d1, Phi2 = n2 / d2;
        cF1 = (float)Phi1; cF2 = (float)Phi2; cF12 = (float)(Phi1 * Phi2);
    }

    const v2f L2E2v = (v2f){(float)L2E2, (float)L2E2};
    const v2f seedA = (v2f){-8.0f/17.0f, -8.0f/17.0f};   // Newton seed slope
    const v2f seedB = (v2f){16.0f/17.0f, 16.0f/17.0f};   // Newton seed offset
    const v2f twov  = (v2f){2.0f, 2.0f};

    __syncthreads();                         // u_s ready

    // ---- state: hs = 2*log2e * h
    v2f hs2[NG];
#pragma unroll
    for (int j = 0; j < NG; ++j) hs2[j] = (v2f){0.0f, 0.0f};   // h = 0

#pragma unroll 1
    for (int tick = 0; tick < NCH + NW - 1; ++tick) {
        const int ch = tick - wv;            // this wave's chunk index
        if (0 <= ch && ch < NCH) {
            // ---- bulk register loads: u's and incoming-B composition
            float4 u4[CH/4];
            float  Tin[CH];
            {
                const float4* up = (const float4*)&u_s[ch * CH];
#pragma unroll
                for (int q = 0; q < CH/4; ++q) u4[q] = up[q];
            }
            if (wv == 0) {
#pragma unroll
                for (int k = 0; k < CH; ++k) Tin[k] = 0.0f;
            } else if (wv == 1) {
                const float4* b0 = (const float4*)&totB_s[0][ch * CH];
#pragma unroll
                for (int q = 0; q < CH/4; ++q) {
                    const float4 v0 = b0[q];
                    Tin[4*q+0] = v0.x; Tin[4*q+1] = v0.y;
                    Tin[4*q+2] = v0.z; Tin[4*q+3] = v0.w;
                }
            } else if (wv == 2) {
                const float4* b0 = (const float4*)&totB_s[0][ch * CH];
                const float4* b1 = (const float4*)&totB_s[1][ch * CH];
#pragma unroll
                for (int q = 0; q < CH/4; ++q) {
                    const float4 v0 = b0[q], v1 = b1[q];
                    Tin[4*q+0] = fmaf(cF1, v0.x, v1.x);
                    Tin[4*q+1] = fmaf(cF1, v0.y, v1.y);
                    Tin[4*q+2] = fmaf(cF1, v0.z, v1.z);
                    Tin[4*q+3] = fmaf(cF1, v0.w, v1.w);
                }
            } else {
                const float4* b0 = (const float4*)&totB_s[0][ch * CH];
                const float4* b1 = (const float4*)&totB_s[1][ch * CH];
                const float4* b2 = (const float4*)&totB_s[2][ch * CH];
#pragma unroll
                for (int q = 0; q < CH/4; ++q) {
                    const float4 v0 = b0[q], v1 = b1[q], v2 = b2[q];
                    Tin[4*q+0] = fmaf(cF12, v0.x, fmaf(cF2, v1.x, v2.x));
                    Tin[4*q+1] = fmaf(cF12, v0.y, fmaf(cF2, v1.y, v2.y));
                    Tin[4*q+2] = fmaf(cF12, v0.z, fmaf(cF2, v1.z, v2.z));
                    Tin[4*q+3] = fmaf(cF12, v0.w, fmaf(cF2, v1.w, v2.w));
                }
            }
            float Bacc[CH];

#pragma unroll
            for (int k = 0; k < CH; ++k) {
                const float u  = ((const float*)&u4[k>>2])[k&3];
                const v2f  uu  = (v2f){u, u};

                // ---- head: W = hs + upc*u  (all in hs scale); gamma
                v2f w2[NG], gam2[NG];
#pragma unroll
                for (int j = 0; j < NG; ++j) {
                    w2[j]   = fma2(upc2[j], uu, hs2[j]);
                    gam2[j] = pdin2[j] * w2[j];
                }

                // ---- local affine scan: two 2-deep chains + compose
                v2f Tb2[NG];
                Tb2[0] = (v2f){0.0f, gam2[0].x};
                const float Tl0 = fmaf(alphas[1], gam2[0].x, gam2[0].y);
                Tb2[1] = (v2f){0.0f, gam2[1].x};
                const float Tl1 = fmaf(alphas[3], gam2[1].x, gam2[1].y);
                Tb2[1] = fma2(aprel2, (v2f){Tl0, Tl0}, Tb2[1]); // hi fixup
                float B = fmaf(apH, Tl0, Tl1);             // lane affine-B

                // ---- cross-lane affine scan (builtin DPP + fma, R10-proven)
                float Bin;
                Bin = dpp_mov<0x111, 0xf>(B, 0.0f); B = fmaf(Alev0, Bin, B);
                Bin = dpp_mov<0x112, 0xf>(B, 0.0f); B = fmaf(Alev1, Bin, B);
                Bin = dpp_mov<0x114, 0xf>(B, 0.0f); B = fmaf(Alev2, Bin, B);
                Bin = dpp_mov<0x118, 0xf>(B, 0.0f); B = fmaf(Alev3, Bin, B);
                Bin = dpp_mov<0x142, 0xa>(B, 0.0f); B = fmaf(Alev4, Bin, B);
                Bin = dpp_mov<0x143, 0xc>(B, 0.0f); B = fmaf(Alev5, Bin, B);
                Bacc[k] = B;                               // publish later

                const float Tst  = dpp_mov<0x138, 0xf>(B, 0.0f); // excl shift
                const float Tent = fmaf(Aexcl, Tin[k], Tst);
                const v2f  Tev   = (v2f){Tent, Tent};

                // ---- elementwise tail, phase-separated; rcp-free tanh
                v2f Tn[NG], tmp[NG], s[NG], z[NG], q[NG];
#pragma unroll
                for (int j = 0; j < NG; ++j) Tn[j]  = fma2(aprod2[j], Tev, Tb2[j]);
#pragma unroll
                for (int j = 0; j < NG; ++j) tmp[j] = fma2(nhdtP2[j], Tn[j], w2[j]);
#pragma unroll
                for (int j = 0; j < NG; ++j) s[j]   = fma2(tmp[j], invd2v[j], -hs2[j]);
#pragma unroll
                for (int j = 0; j < NG; ++j) {
                    const v2f na = min2(s[j], -s[j]);      // -|s|
                    z[j].x = EXP2F(na.x);
                    z[j].y = EXP2F(na.y);
                }
                // q = 1/(1+z), Newton x2 from seed 16/17 - 8/17*z
#pragma unroll
                for (int j = 0; j < NG; ++j) q[j] = fma2(seedA, z[j], seedB);
#pragma unroll
                for (int j = 0; j < NG; ++j) {
                    const v2f yq = fma2(z[j], q[j], q[j]); // (1+z)q
                    q[j] = q[j] * (twov - yq);
                }
#pragma unroll
                for (int j = 0; j < NG; ++j) {
                    const v2f yq = fma2(z[j], q[j], q[j]);
                    q[j] = q[j] * (twov - yq);
                }
                // t = (1-z)q = tanh(|g|);  hs' = copysign(L2E2*t, s)
#pragma unroll
                for (int j = 0; j < NG; ++j) {
                    const v2f t   = fma2(-z[j], q[j], q[j]);
                    const v2f hst = L2E2v * t;
                    hs2[j].x = copysignf(hst.x, s[j].x);
                    hs2[j].y = copysignf(hst.y, s[j].y);
                }
            }

            // publish this wave's chunk B-totals (lane 63 holds them)
            if (wv < NW - 1 && lane == 63) {
                float4* tp = (float4*)&totB_s[wv][ch * CH];
#pragma unroll
                for (int q = 0; q < CH/4; ++q)
                    tp[q] = make_float4(Bacc[4*q], Bacc[4*q+1],
                                        Bacc[4*q+2], Bacc[4*q+3]);
            }
        }
        __syncthreads();   // one barrier per CHUNK (16 steps)
    }

    // ---- epilogue: h = hs/L2E2; tot = dot(h, C) over this wave's 256 elems
    double acc = 0.0;
#pragma unroll
    for (int i = 0; i < EPL; ++i)
        acc = fma((double)C[wv * 256 + lane * EPL + i],
                  (double)hs2[i>>1][i&1], acc);
#pragma unroll
    for (int off = 32; off > 0; off >>= 1)
        acc += __shfl_down(acc, off, 64);
    if (lane == 0) part_s[wv] = acc;
    __syncthreads();
    if (tid < OUT_DIM) {
        const double tot = (part_s[0] + part_s[1] + part_s[2] + part_s[3])
                           / (2.0 * 1.4426950408889634);
        out[b * OUT_DIM + tid] =
            (float)fma(tot, (double)W[tid], (double)bvec[tid]);
    }
}

extern "C" void kernel_launch(void* const* d_in, const int* in_sizes, int n_in,
                              void* d_out, int out_size, void* d_ws, size_t ws_size,
                              hipStream_t stream) {
    const float* x  = (const float*)d_in[0];   // (512, 784, 1)
    const float* C  = (const float*)d_in[1];   // (1, 1024)
    const float* W  = (const float*)d_in[2];   // (1, 10)
    const float* bv = (const float*)d_in[3];   // (10,)
    float* out      = (float*)d_out;           // (512, 10)
    hipLaunchKernelGGL(ssm_hippo_scan, dim3(512), dim3(256), 0, stream,
                       x, C, W, bv, out);
}

// Round 13
// 272.742 us; speedup vs baseline: 1.0858x; 1.0858x over previous
//
#include <hip/hip_runtime.h>
#include <math.h>

// SSM_18597208391915: HiPPO-LegT recurrence, O(N) semiseparable solve.
// Ad = (I-cA)^{-1}(I+cA) = 2M - I  =>  h' = tanh(2*M(h + c*u*P) - h).
// R10 (BEST, 231us rocprof): NW=4 chunked skewed wave pipeline, 2 indep
// waves/SIMD (256-thr blocks, 2 blocks/CU, co-waves from different batch
// elems hide each other's stalls). R11/R12 post-mortem: Newton-rcp tanh is
// a net LOSS (v_rcp is only ~8cyc issue at wave64; +52cyc of full-rate fma
// to save ~36cyc of trans) -- exp2+rcp sigmoid is the cheapest tanh here.
// R13 = R10 exactly, with CH 16->28 (784=28x28): ticks 53->31, fewer
// barrier drains, chunk-edge costs (u/Tin loads, publish) amortized 1.75x.

#define SEQ     784
#define OUT_DIM 10
#define NW      4
#define CH      28            // steps per chunk (784 = 28*28)
#define NCH     (SEQ/CH)      // 28
#define EPL     4             // elems/lane: NW*64*EPL = 1024 = HIDDEN
#define NG      (EPL/2)

typedef float v2f __attribute__((ext_vector_type(2)));

#if __has_builtin(__builtin_elementwise_fma)
__device__ __forceinline__ v2f fma2(v2f a, v2f b, v2f c) {
    return __builtin_elementwise_fma(a, b, c);
}
#else
__device__ __forceinline__ v2f fma2(v2f a, v2f b, v2f c) {
    v2f r; r.x = fmaf(a.x, b.x, c.x); r.y = fmaf(a.y, b.y, c.y); return r;
}
#endif

#if __has_builtin(__builtin_amdgcn_exp2f)
#define EXP2F(x) __builtin_amdgcn_exp2f(x)
#else
#define EXP2F(x) __expf(0.69314718055994531f * (x))
#endif

// DPP move: result = src shuffled per CTRL; invalid/masked lanes get `old`.
// (builtin form: compiler handles the VALU->DPP hazard wait states)
template<int CTRL, int ROW_MASK>
__device__ __forceinline__ float dpp_mov(float src, float old) {
    return __int_as_float(__builtin_amdgcn_update_dpp(
        __float_as_int(old), __float_as_int(src), CTRL, ROW_MASK, 0xf, false));
}
// DPP ctrls: row_shr:N = 0x110|N, row_bcast15 = 0x142, row_bcast31 = 0x143,
//            wave_shr:1 = 0x138 (whole-wave shift down one lane)

__global__ __launch_bounds__(256, 2)
void ssm_hippo_scan(const float* __restrict__ x,     // (512, 784)
                    const float* __restrict__ C,     // (1024)
                    const float* __restrict__ W,     // (10)
                    const float* __restrict__ bvec,  // (10)
                    float* __restrict__ out)         // (512, 10)
{
    const int b    = blockIdx.x;
    const int tid  = threadIdx.x;
    const int wv   = tid >> 6;       // wave w owns elems [w*256, w*256+256)
    const int lane = tid & 63;

    __shared__ __align__(16) float u_s[SEQ];
    __shared__ __align__(16) float totB_s[NW-1][SEQ]; // inclusive-B streams
    __shared__ double part_s[NW];

    for (int t = tid; t < SEQ; t += 256) u_s[t] = x[b * SEQ + t];

    const double hdt  = 0.5 / (double)SEQ;            // c = dt/2
    const double L2E2 = 2.0 * 1.4426950408889634;     // 2*log2(e)

    // ---- per-element constants (n = wv*256 + lane*EPL + i), fp64-derived
    v2f upc2[NG], nhdtP2[NG], pdin2[NG], invd2v[NG], aprod2[NG];
    v2f aprel2;                 // {1, alphas[2]}: hi-chain fixup
    float alphas[EPL], apH;
    float Alev0, Alev1, Alev2, Alev3, Alev4, Alev5, Aexcl;
    {
        double apd = 1.0;
#pragma unroll
        for (int i = 0; i < EPL; ++i) {
            const int    n = wv * 256 + lane * EPL + i;
            const double p = sqrt(1.0 + 2.0 * (double)n);
            const double d = 1.0 + hdt * (double)(n + 1);
            const double a = 1.0 - hdt * p * p / d;
            upc2[i>>1][i&1]   = (float)(L2E2 * hdt * p);
            nhdtP2[i>>1][i&1] = (float)(-hdt * p);
            pdin2[i>>1][i&1]  = (float)(p / d);
            invd2v[i>>1][i&1] = (float)(2.0 / d);
            alphas[i]         = (float)a;
            aprod2[i>>1][i&1] = (float)apd;
            apd *= a;
        }
        aprel2 = (v2f){1.0f, alphas[2]};
        apH    = alphas[2] * alphas[3];
        float A = (float)apd;
        Alev0 = A; A *= dpp_mov<0x111, 0xf>(A, 1.0f);
        Alev1 = A; A *= dpp_mov<0x112, 0xf>(A, 1.0f);
        Alev2 = A; A *= dpp_mov<0x114, 0xf>(A, 1.0f);
        Alev3 = A; A *= dpp_mov<0x118, 0xf>(A, 1.0f);
        Alev4 = A; A *= dpp_mov<0x142, 0xa>(A, 1.0f);
        Alev5 = A; A *= dpp_mov<0x143, 0xc>(A, 1.0f);
        Aexcl = dpp_mov<0x138, 0xf>(A, 1.0f);   // lane0 -> 1 (excl alpha prod)
    }

    // inter-wave composition: Tin(w)[s] = sum_{v<w} cin_v * B_v[s]
    float cF1 = 0.0f, cF2 = 0.0f, cF12 = 0.0f;
    {
        double n1 = 1.0, d1 = 1.0, n2 = 1.0, d2 = 1.0;
        for (int n = 256; n < 512; ++n) {
            n1 *= 1.0 - hdt * (double)n; d1 *= 1.0 + hdt * (double)(n + 1);
        }
        for (int n = 512; n < 768; ++n) {
            n2 *= 1.0 - hdt * (double)n; d2 *= 1.0 + hdt * (double)(n + 1);
        }
        const double Phi1 = n1 / d1, Phi2 = n2 / d2;
        cF1 = (float)Phi1; cF2 = (float)Phi2; cF12 = (float)(Phi1 * Phi2);
    }

    const float c2  = (float)L2E2;           //  2*log2e
    const float nc4 = (float)(-2.0 * L2E2);  // -4*log2e  (Hs = nc4*r + c2)
    const float p4  = (float)(2.0 * L2E2);   //  (-Hs = p4*r - c2)
    const v2f  c2v  = (v2f){c2, c2},  nc2v = (v2f){-c2, -c2};
    const v2f  nc4v = (v2f){nc4, nc4}, p4v = (v2f){p4, p4};

    __syncthreads();                         // u_s ready

    // ---- state: r (sigmoid form, h = 1-2r)
    v2f r2[NG];
#pragma unroll
    for (int j = 0; j < NG; ++j) r2[j] = (v2f){0.5f, 0.5f};   // h = 0

#pragma unroll 1
    for (int tick = 0; tick < NCH + NW - 1; ++tick) {
        const int ch = tick - wv;            // this wave's chunk index
        if (0 <= ch && ch < NCH) {
            // ---- bulk register loads: u's and incoming-B composition
            float4 u4[CH/4];
            float  Tin[CH];
            {
                const float4* up = (const float4*)&u_s[ch * CH];
#pragma unroll
                for (int q = 0; q < CH/4; ++q) u4[q] = up[q];
            }
            if (wv == 0) {
#pragma unroll
                for (int k = 0; k < CH; ++k) Tin[k] = 0.0f;
            } else if (wv == 1) {
                const float4* b0 = (const float4*)&totB_s[0][ch * CH];
#pragma unroll
                for (int q = 0; q < CH/4; ++q) {
                    const float4 v0 = b0[q];
                    Tin[4*q+0] = v0.x; Tin[4*q+1] = v0.y;
                    Tin[4*q+2] = v0.z; Tin[4*q+3] = v0.w;
                }
            } else if (wv == 2) {
                const float4* b0 = (const float4*)&totB_s[0][ch * CH];
                const float4* b1 = (const float4*)&totB_s[1][ch * CH];
#pragma unroll
                for (int q = 0; q < CH/4; ++q) {
                    const float4 v0 = b0[q], v1 = b1[q];
                    Tin[4*q+0] = fmaf(cF1, v0.x, v1.x);
                    Tin[4*q+1] = fmaf(cF1, v0.y, v1.y);
                    Tin[4*q+2] = fmaf(cF1, v0.z, v1.z);
                    Tin[4*q+3] = fmaf(cF1, v0.w, v1.w);
                }
            } else {
                const float4* b0 = (const float4*)&totB_s[0][ch * CH];
                const float4* b1 = (const float4*)&totB_s[1][ch * CH];
                const float4* b2 = (const float4*)&totB_s[2][ch * CH];
#pragma unroll
                for (int q = 0; q < CH/4; ++q) {
                    const float4 v0 = b0[q], v1 = b1[q], v2 = b2[q];
                    Tin[4*q+0] = fmaf(cF12, v0.x, fmaf(cF2, v1.x, v2.x));
                    Tin[4*q+1] = fmaf(cF12, v0.y, fmaf(cF2, v1.y, v2.y));
                    Tin[4*q+2] = fmaf(cF12, v0.z, fmaf(cF2, v1.z, v2.z));
                    Tin[4*q+3] = fmaf(cF12, v0.w, fmaf(cF2, v1.w, v2.w));
                }
            }
            float Bacc[CH];

#pragma unroll
            for (int k = 0; k < CH; ++k) {
                const float u  = ((const float*)&u4[k>>2])[k&3];
                const v2f  uu  = (v2f){u, u};

                // ---- head: w = Hs + upc*u (Hs = nc4*r + c2); gamma; -Hs
                v2f w2[NG], gam2[NG], negh[NG];
#pragma unroll
                for (int j = 0; j < NG; ++j) {
                    const v2f au = fma2(upc2[j], uu, c2v);
                    w2[j]   = fma2(nc4v, r2[j], au);
                    gam2[j] = pdin2[j] * w2[j];
                    negh[j] = fma2(p4v, r2[j], nc2v);
                }

                // ---- local affine scan: two 2-deep chains + compose
                v2f Tb2[NG];
                Tb2[0] = (v2f){0.0f, gam2[0].x};
                const float Tl0 = fmaf(alphas[1], gam2[0].x, gam2[0].y);
                Tb2[1] = (v2f){0.0f, gam2[1].x};
                const float Tl1 = fmaf(alphas[3], gam2[1].x, gam2[1].y);
                Tb2[1] = fma2(aprel2, (v2f){Tl0, Tl0}, Tb2[1]); // hi fixup
                float B = fmaf(apH, Tl0, Tl1);             // lane affine-B

                // ---- cross-lane affine scan (B chain, A's precomputed)
                float Bin;
                Bin = dpp_mov<0x111, 0xf>(B, 0.0f); B = fmaf(Alev0, Bin, B);
                Bin = dpp_mov<0x112, 0xf>(B, 0.0f); B = fmaf(Alev1, Bin, B);
                Bin = dpp_mov<0x114, 0xf>(B, 0.0f); B = fmaf(Alev2, Bin, B);
                Bin = dpp_mov<0x118, 0xf>(B, 0.0f); B = fmaf(Alev3, Bin, B);
                Bin = dpp_mov<0x142, 0xa>(B, 0.0f); B = fmaf(Alev4, Bin, B);
                Bin = dpp_mov<0x143, 0xc>(B, 0.0f); B = fmaf(Alev5, Bin, B);
                Bacc[k] = B;                               // publish later

                const float Tst  = dpp_mov<0x138, 0xf>(B, 0.0f); // excl shift
                const float Tent = fmaf(Aexcl, Tin[k], Tst);
                const v2f  Tev   = (v2f){Tent, Tent};

                // ---- elementwise tail, phase-separated
                v2f Tn[NG], tmp[NG], g2l[NG], e[NG];
#pragma unroll
                for (int j = 0; j < NG; ++j) Tn[j]  = fma2(aprod2[j], Tev, Tb2[j]);
#pragma unroll
                for (int j = 0; j < NG; ++j) tmp[j] = fma2(nhdtP2[j], Tn[j], w2[j]);
#pragma unroll
                for (int j = 0; j < NG; ++j) g2l[j] = fma2(tmp[j], invd2v[j], negh[j]);
#pragma unroll
                for (int j = 0; j < NG; ++j) { e[j].x = EXP2F(g2l[j].x);
                                               e[j].y = EXP2F(g2l[j].y); }
#pragma unroll
                for (int j = 0; j < NG; ++j) e[j] = e[j] + (v2f){1.0f, 1.0f};
#pragma unroll
                for (int j = 0; j < NG; ++j) { r2[j].x = __builtin_amdgcn_rcpf(e[j].x);
                                               r2[j].y = __builtin_amdgcn_rcpf(e[j].y); }
            }

            // publish this wave's chunk B-totals (lane 63 holds them)
            if (wv < NW - 1 && lane == 63) {
                float4* tp = (float4*)&totB_s[wv][ch * CH];
#pragma unroll
                for (int q = 0; q < CH/4; ++q)
                    tp[q] = make_float4(Bacc[4*q], Bacc[4*q+1],
                                        Bacc[4*q+2], Bacc[4*q+3]);
            }
        }
        __syncthreads();   // one barrier per CHUNK (28 steps)
    }

    // ---- epilogue: h = 1-2r; tot = dot(h, C) over this wave's 256 elems
    double acc = 0.0;
#pragma unroll
    for (int i = 0; i < EPL; ++i) {
        const float hi = fmaf(-2.0f, r2[i>>1][i&1], 1.0f);
        acc = fma((double)C[wv * 256 + lane * EPL + i], (double)hi, acc);
    }
#pragma unroll
    for (int off = 32; off > 0; off >>= 1)
        acc += __shfl_down(acc, off, 64);
    if (lane == 0) part_s[wv] = acc;
    __syncthreads();
    if (tid < OUT_DIM) {
        const double tot = part_s[0] + part_s[1] + part_s[2] + part_s[3];
        out[b * OUT_DIM + tid] =
            (float)fma(tot, (double)W[tid], (double)bvec[tid]);
    }
}

extern "C" void kernel_launch(void* const* d_in, const int* in_sizes, int n_in,
                              void* d_out, int out_size, void* d_ws, size_t ws_size,
                              hipStream_t stream) {
    const float* x  = (const float*)d_in[0];   // (512, 784, 1)
    const float* C  = (const float*)d_in[1];   // (1, 1024)
    const float* W  = (const float*)d_in[2];   // (1, 10)
    const float* bv = (const float*)d_in[3];   // (10,)
    float* out      = (float*)d_out;           // (512, 10)
    hipLaunchKernelGGL(ssm_hippo_scan, dim3(512), dim3(256), 0, stream,
                       x, C, W, bv, out);
}